// Round 1
// 237.275 us; speedup vs baseline: 1.0061x; 1.0061x over previous
//
#include <hip/hip_runtime.h>
#include <hip/hip_bf16.h>

// Gram matrix: G = X @ X^T, X = [512, 65536] fp32, out = [512, 512] fp32.
// Round 11: counters show r10 is LATENCY-bound (MfmaUtil 8.4 / VALUBusy 7.8 /
// HBM 28% / Occ 17.9 -- everything idle). Structural change: replace the
// reg-staged  global->VGPR->cvt->LDS  path with ASYNC fp32 staging via
// __builtin_amdgcn_global_load_lds (16B/lane), converting fp32->bf16 at
// fragment-read time instead (VALU was at 8% -- headroom).
//   - LDS holds fp32 panels [128][32] (16 KB each, 32 KB/block). Since
//     global_load_lds writes linearly, bank conflicts on the 128B-stride rows
//     are fixed by PRE-SWIZZLING the per-lane global source (slot ^= row&7)
//     and XOR-ing the same on ds_read_b128 addresses (guide G21: both-sides).
//   - uniform chunking for balance: ALL 10 unique tiles split into 64 chunks
//     of KC=1024 (32 iters) -> grid 640 (upper 384 first, diag 256 after).
//     r10's diag blocks (64 iters, half loads) were the 1.5x critical path.
//   - occupancy: 32 KB LDS -> up to 5 blocks/CU resident (r10: 2).
//   - epilogue/mirror/memset unchanged (r1's proven coalesced atomics;
//     10.5M atomics vs 8.4M, ~+4 us per r6's scaling -- balance pays for it).
// History: r1 fused 135us; r9 LDS-free 170us (latency); r10 symmetric 100us.

typedef short bf16x8 __attribute__((ext_vector_type(8)));   // 8 bf16 = 4 VGPRs
typedef float f32x4  __attribute__((ext_vector_type(4)));   // MFMA acc

#define HW    65536
#define CDIM  512

__device__ __forceinline__ short f2bf(float f) {
    __hip_bfloat16 h = __float2bfloat16(f);   // RNE
    short s;
    __builtin_memcpy(&s, &h, sizeof(short));
    return s;
}

__device__ __forceinline__ bf16x8 cvt8(float4 a, float4 b) {
    bf16x8 v;
    v[0] = f2bf(a.x); v[1] = f2bf(a.y); v[2] = f2bf(a.z); v[3] = f2bf(a.w);
    v[4] = f2bf(b.x); v[5] = f2bf(b.y); v[6] = f2bf(b.z); v[7] = f2bf(b.w);
    return v;
}

// async global->LDS, 16 bytes per lane (dest = wave-uniform base + lane*16)
__device__ __forceinline__ void gload16(const float* g, float* l) {
    __builtin_amdgcn_global_load_lds(
        (const __attribute__((address_space(1))) void*)g,
        (__attribute__((address_space(3))) void*)l,
        16, 0, 0);
}

__global__ __launch_bounds__(256, 2)
void gram_kernel(const float* __restrict__ X, float* __restrict__ out) {
    // decode: p<384 -> upper tile o=p>>6 ; p>=384 -> diag tile (p-384)>>6.
    // all chunks: KC = 1024 (chunk = p&63, both segments 64-aligned), 32 iters.
    const int p = blockIdx.x;
    int ti, tj;
    if (p < 384) {
        const int o = p >> 6;
        const int TI[6] = {0, 0, 0, 1, 1, 2};
        const int TJ[6] = {1, 2, 3, 2, 3, 3};
        ti = TI[o]; tj = TJ[o];
    } else {
        ti = tj = (p - 384) >> 6;
    }
    const int kbase = (p & 63) << 10;
    const bool diag = (ti == tj);

    // fp32 panels, linear [128][32] (stride 128 B) -- swizzle lives in the
    // source permutation + read addressing, NOT the layout (global_load_lds
    // requires a linear destination).
    __shared__ float As[128 * 32];
    __shared__ float Bs[128 * 32];

    const int t    = threadIdx.x;
    const int wave = t >> 6;
    const int lane = t & 63;
    const int wm   = wave & 1;          // 2x2 wave grid, each wave = 64x64
    const int wn   = wave >> 1;

    // --- staging: thread t covers row (t>>3)+32r, 16B slot (t&7), r=0..3 ---
    // LDS slot s holds global k-slot s ^ (row&7)  (pre-swizzled source).
    // (row&7) == ((t>>3)&7) for every round r since 32r == 0 (mod 8).
    const int srow = t >> 3;                       // 0..31
    const int sswz = (t & 7) ^ (srow & 7);
    const float* ga = X + (size_t)(ti * 128 + srow) * HW + kbase + sswz * 4;
    const float* gb = X + (size_t)(tj * 128 + srow) * HW + kbase + sswz * 4;
    float* la = As + t * 4;                        // byte off = t*16 (+ r*4096)
    float* lb = Bs + t * 4;

    // --- fragment read offsets (float units), two swizzled 16B halves each ---
    const int fm = lane & 15;
    const int kg = lane >> 4;           // k-group: 8 contiguous k = slots 2kg,2kg+1
    int a_off0[4], a_off1[4], b_off0[4], b_off1[4];
#pragma unroll
    for (int i = 0; i < 4; ++i) {
        const int ra = wm * 64 + i * 16 + fm;
        a_off0[i] = ra * 32 + ((( 2 * kg    ) ^ (ra & 7)) << 2);
        a_off1[i] = ra * 32 + (((2 * kg + 1) ^ (ra & 7)) << 2);
        const int rb = wn * 64 + i * 16 + fm;
        b_off0[i] = rb * 32 + ((( 2 * kg    ) ^ (rb & 7)) << 2);
        b_off1[i] = rb * 32 + (((2 * kg + 1) ^ (rb & 7)) << 2);
    }
    const float* Bbase = diag ? As : Bs;   // diag: B frags read the A panel

    f32x4 acc[4][4];
#pragma unroll
    for (int i = 0; i < 4; ++i)
#pragma unroll
        for (int j = 0; j < 4; ++j)
            acc[i][j] = (f32x4){0.f, 0.f, 0.f, 0.f};

    for (int it = 0; it < 32; ++it) {
        // async stage: 4 (8 if off-diag) x global_load_lds, 16B per lane
#pragma unroll
        for (int r = 0; r < 4; ++r)
            gload16(ga + (size_t)r * 32 * HW, la + r * 1024);
        if (!diag) {
#pragma unroll
            for (int r = 0; r < 4; ++r)
                gload16(gb + (size_t)r * 32 * HW, lb + r * 1024);
        }
        __syncthreads();   // compiler drains vmcnt(0): stage visible

        // LDS fp32 -> bf16 fragments (cvt at read; VALU has 10x headroom)
        bf16x8 af[4], bfr[4];
#pragma unroll
        for (int i = 0; i < 4; ++i) {
            const float4 h0 = *(const float4*)(As + a_off0[i]);
            const float4 h1 = *(const float4*)(As + a_off1[i]);
            af[i] = cvt8(h0, h1);
        }
#pragma unroll
        for (int j = 0; j < 4; ++j) {
            const float4 h0 = *(const float4*)(Bbase + b_off0[j]);
            const float4 h1 = *(const float4*)(Bbase + b_off1[j]);
            bfr[j] = cvt8(h0, h1);
        }

#pragma unroll
        for (int i = 0; i < 4; ++i)
#pragma unroll
            for (int j = 0; j < 4; ++j)
                acc[i][j] = __builtin_amdgcn_mfma_f32_16x16x32_bf16(
                    af[i], bfr[j], acc[i][j], 0, 0, 0);

        __syncthreads();   // LDS reads done before next overwrite
        ga += 32;
        gb += 32;
    }

    // --- epilogue: row-major coalesced atomics (diag/upper tiles only) ---
    // C/D layout (verified m89/m91): col = lane&15, row = (lane>>4)*4 + reg
    const int orow0 = ti * 128 + wm * 64 + (lane >> 4) * 4;
    const int ocol0 = tj * 128 + wn * 64 + fm;
#pragma unroll
    for (int i = 0; i < 4; ++i)
#pragma unroll
        for (int j = 0; j < 4; ++j)
#pragma unroll
            for (int r = 0; r < 4; ++r)
                atomicAdd(out + (orow0 + i * 16 + r) * CDIM + ocol0 + j * 16,
                          acc[i][j][r]);
}

// ---------------- mirror: copy upper tiles transposed into lower ----------------
__global__ __launch_bounds__(256)
void mirror_kernel(float* __restrict__ out) {
    const int id = blockIdx.x * 256 + threadIdx.x;   // 0..262143
    const int r = id >> 9;
    const int c = id & 511;
    if ((r >> 7) > (c >> 7))
        out[id] = out[c * CDIM + r];
}

extern "C" void kernel_launch(void* const* d_in, const int* in_sizes, int n_in,
                              void* d_out, int out_size, void* d_ws, size_t ws_size,
                              hipStream_t stream) {
    const float* x = (const float*)d_in[0];
    float* out = (float*)d_out;

    // zero the accumulator (harness poisons d_out with 0xAA before every launch)
    hipMemsetAsync(d_out, 0, (size_t)out_size * sizeof(float), stream);

    gram_kernel<<<dim3(640), dim3(256), 0, stream>>>(x, out);
    mirror_kernel<<<dim3(1024), dim3(256), 0, stream>>>(out);
}